// Round 6
// baseline (599.402 us; speedup 1.0000x reference)
//
#include <hip/hip_runtime.h>
#include <hip/hip_bf16.h>
#include <cstdint>

typedef __attribute__((ext_vector_type(8))) short bf16x8;   // 8 bf16 bit-patterns
typedef __attribute__((ext_vector_type(4))) float f32x4;

#define AS1 __attribute__((address_space(1)))
#define AS3 __attribute__((address_space(3)))

__device__ __forceinline__ void gload16(const void* g, void* l) {
  __builtin_amdgcn_global_load_lds((const AS1 unsigned int*)g,
                                   (AS3 unsigned int*)l, 16, 0, 0);
}

__device__ __forceinline__ unsigned short f2bf(float f) {
  unsigned int u = __builtin_bit_cast(unsigned int, f);
  u += 0x7FFFu + ((u >> 16) & 1u);           // RNE
  return (unsigned short)(u >> 16);
}

// exact-erf GELU via Abramowitz-Stegun 7.1.26 (|erf err| <= 1.5e-7), branch-free
__device__ __forceinline__ float fast_gelu(float x) {
  float z = fabsf(x) * 0.70710678118654752f;
  float t = __builtin_amdgcn_rcpf(1.0f + 0.3275911f * z);
  float poly = t * (0.254829592f + t * (-0.284496736f + t * (1.421413741f +
               t * (-1.453152027f + t * 1.061405429f))));
  float erf_abs = 1.0f - poly * __expf(-z * z);
  float erfv = (x < 0.0f) ? -erf_abs : erf_abs;
  return 0.5f * x * (1.0f + erfv);
}

// ---------------- fused fp32 -> bf16 convert (all 4 weights, 1 launch) -------
__global__ __launch_bounds__(256) void cvt_all(
    const float* __restrict__ s0, unsigned short* __restrict__ d0, int n0,
    const float* __restrict__ s1, unsigned short* __restrict__ d1, int n1,
    const float* __restrict__ s2, unsigned short* __restrict__ d2, int n2,
    const float* __restrict__ s3, unsigned short* __restrict__ d3, int n3) {
  int total = n0 + n1 + n2 + n3;
  int stride = gridDim.x * 256;
  for (int i = blockIdx.x * 256 + threadIdx.x; i < total; i += stride) {
    const float* s; unsigned short* d; int j = i;
    if (j < n0) { s = s0; d = d0; }
    else if ((j -= n0) < n1) { s = s1; d = d1; }
    else if ((j -= n1) < n2) { s = s2; d = d2; }
    else { j -= n2; s = s3; d = d3; }
    float4 v = ((const float4*)s)[j];
    ushort4 st;
    st.x = f2bf(v.x); st.y = f2bf(v.y); st.z = f2bf(v.z); st.w = f2bf(v.w);
    ((ushort4*)d)[j] = st;
  }
}

// ---------------- LayerNorm (row=1024) -> bf16 ----------------
__global__ __launch_bounds__(256) void ln_kernel(const float* __restrict__ x,
                                                 const float* __restrict__ gw,
                                                 const float* __restrict__ bw,
                                                 unsigned short* __restrict__ out,
                                                 int rows) {
  int row = blockIdx.x;
  if (row >= rows) return;
  const float4* xr = (const float4*)(x + (size_t)row * 1024);
  int tid = threadIdx.x;
  float4 v = xr[tid];
  float s = v.x + v.y + v.z + v.w;
  float s2 = v.x * v.x + v.y * v.y + v.z * v.z + v.w * v.w;
  #pragma unroll
  for (int m = 1; m < 64; m <<= 1) { s += __shfl_xor(s, m); s2 += __shfl_xor(s2, m); }
  __shared__ float ls[4], ls2[4];
  int wv = tid >> 6;
  if ((tid & 63) == 0) { ls[wv] = s; ls2[wv] = s2; }
  __syncthreads();
  s = ls[0] + ls[1] + ls[2] + ls[3];
  s2 = ls2[0] + ls2[1] + ls2[2] + ls2[3];
  float mu = s * (1.0f / 1024.0f);
  float var = s2 * (1.0f / 1024.0f) - mu * mu;
  float rs = rsqrtf(var + 1e-5f);
  float4 g4 = ((const float4*)gw)[tid];
  float4 b4 = ((const float4*)bw)[tid];
  ushort4 st;
  st.x = f2bf((v.x - mu) * rs * g4.x + b4.x);
  st.y = f2bf((v.y - mu) * rs * g4.y + b4.y);
  st.z = f2bf((v.z - mu) * rs * g4.z + b4.z);
  st.w = f2bf((v.w - mu) * rs * g4.w + b4.w);
  ((ushort4*)(out + (size_t)row * 1024))[tid] = st;
}

// ---------------- 128x128 BK=32 B^T GEMM (m103's 912-TF config) -------------
// Round-0 2-phase schedule, geometry only changed: 256 threads (4 waves, 2x2),
// wave tile 64x64, acc[4][4], 32 KiB LDS -> 5 blocks/CU co-residency.
// Per K-step/wave: 16 MFMA : 8 ds_read_b128 (same ratio as round-0);
// 4 gload16/thread staging -> vmcnt(4).
template<int EPI>
__global__ __launch_bounds__(256) void gemm_s(
    const unsigned short* __restrict__ A, const unsigned short* __restrict__ B,
    int M, int N, int K, int CP,
    const float* __restrict__ bias0, const float* __restrict__ bias1,
    const float* __restrict__ resid,
    unsigned short* __restrict__ o0, unsigned short* __restrict__ o1,
    unsigned short* __restrict__ o2, float* __restrict__ f_out) {
  extern __shared__ unsigned short smem[];   // 16384 ushorts = 32 KiB
  const int tid = threadIdx.x;
  const int lane = tid & 63;
  const int wid = tid >> 6;       // 0..3
  const int wr = wid >> 1;        // 0..1 (M half, 64 rows)
  const int wc = wid & 1;         // 0..1 (N half, 64 cols)
  const int lane15 = lane & 15, l16 = lane >> 4;

  const int nwg = gridDim.x;
  const int bid = blockIdx.x;
  const int q = nwg >> 3, rmd = nwg & 7;
  const int xcd = bid & 7, idx = bid >> 3;
  const int s = (xcd < rmd ? xcd * (q + 1) : rmd * (q + 1) + (xcd - rmd) * q) + idx;
  const int brow = s / CP, bcol = s - brow * CP;
  const long row0 = (long)brow * 128;
  const long col0 = (long)bcol * 128;
  const int NT = K >> 5;

  const int srow = tid >> 2;                 // 0..63
  const int scol = (tid & 3) * 8;            // element col within 32-elem row
  const int sdst = tid << 3;                 // ushort offset (row-major [64][32])

  auto stageAll = [&](int t) {
    const int buf = t & 1;
    const long kofs = (long)t * 32 + scol;
    unsigned short* Ad = smem + buf * 4096 + sdst;
    gload16(A + (row0 + srow) * (long)K + kofs, Ad);
    gload16(A + (row0 + 64 + srow) * (long)K + kofs, Ad + 2048);
    unsigned short* Bd = smem + 8192 + buf * 4096 + sdst;
    gload16(B + (col0 + srow) * (long)K + kofs, Bd);
    gload16(B + (col0 + 64 + srow) * (long)K + kofs, Bd + 2048);
  };

  f32x4 acc[4][4] = {};

  stageAll(0);

  for (int t = 0; t < NT; ++t) {
    if (t + 1 < NT) { stageAll(t + 1);
                      asm volatile("s_waitcnt vmcnt(4)" ::: "memory"); }
    else            { asm volatile("s_waitcnt vmcnt(0)" ::: "memory"); }
    __builtin_amdgcn_s_barrier();

    const unsigned short* Acur = smem + (t & 1) * 4096;
    const unsigned short* Bcur = smem + 8192 + (t & 1) * 4096;
    bf16x8 afrag[4], bfrag[4];
    #pragma unroll
    for (int mi = 0; mi < 4; ++mi)
      afrag[mi] = *(const bf16x8*)(Acur + (wr * 64 + mi * 16 + lane15) * 32 + l16 * 8);
    #pragma unroll
    for (int ni = 0; ni < 4; ++ni)
      bfrag[ni] = *(const bf16x8*)(Bcur + (wc * 64 + ni * 16 + lane15) * 32 + l16 * 8);
    asm volatile("s_waitcnt lgkmcnt(0)" ::: "memory");
    __builtin_amdgcn_sched_barrier(0);
    __builtin_amdgcn_s_setprio(1);
    #pragma unroll
    for (int mi = 0; mi < 4; ++mi)
      #pragma unroll
      for (int ni = 0; ni < 4; ++ni)
        acc[mi][ni] = __builtin_amdgcn_mfma_f32_16x16x32_bf16(
            afrag[mi], bfrag[ni], acc[mi][ni], 0, 0, 0);
    __builtin_amdgcn_s_setprio(0);
    __builtin_amdgcn_s_barrier();
  }

  // ---------------- epilogue ----------------
  const int lrow = l16 * 4;
  if constexpr (EPI == 0) {
    const int colbase = (int)col0 + wc * 64;
    const int part = colbase >> 10;
    const int hd0 = colbase & 1023;
    const int head = hd0 >> 6;
    unsigned short* dst = (part == 0) ? o0 : (part == 1 ? o1 : o2);
    const float scl = (part == 0) ? 0.125f : 1.0f;
    float bias[4];
    #pragma unroll
    for (int ni = 0; ni < 4; ++ni) {
      int hd = hd0 + ni * 16 + lane15;
      bias[ni] = (part == 0) ? bias0[hd] : (part == 2 ? bias1[hd] : 0.0f);
    }
    #pragma unroll
    for (int mi = 0; mi < 4; ++mi) {
      #pragma unroll
      for (int r = 0; r < 4; ++r) {
        int irow = (int)row0 + wr * 64 + mi * 16 + lrow + r;
        if (irow >= M) continue;
        int bb = irow / 197, tk = irow - bb * 197;
        long obase = ((long)(bb * 16 + head) * 197 + tk) * 64;
        #pragma unroll
        for (int ni = 0; ni < 4; ++ni)
          dst[obase + ni * 16 + lane15] = f2bf((acc[mi][ni][r] + bias[ni]) * scl);
      }
    }
  } else {
    float bias[4];
    #pragma unroll
    for (int ni = 0; ni < 4; ++ni)
      bias[ni] = bias0[col0 + wc * 64 + ni * 16 + lane15];
    #pragma unroll
    for (int mi = 0; mi < 4; ++mi) {
      #pragma unroll
      for (int r = 0; r < 4; ++r) {
        long row = row0 + wr * 64 + mi * 16 + lrow + r;
        if (row >= M) continue;
        long cbase = col0 + wc * 64 + lane15;
        #pragma unroll
        for (int ni = 0; ni < 4; ++ni) {
          long col = cbase + ni * 16;
          float cv = acc[mi][ni][r] + bias[ni];
          if constexpr (EPI == 2) {
            o0[row * (long)N + col] = f2bf(fast_gelu(cv));
          } else {
            f_out[row * 1024 + col] = cv + resid[row * 1024 + col];
          }
        }
      }
    }
  }
}

// ---------------- rel-pos bias table build: bt[16][208][224] bf16 ------------
__device__ __forceinline__ int relidx(int q, int k) {
  if (q == 0) return (k == 0) ? 731 : 729;
  if (k == 0) return 730;
  int qp = q - 1, kp = k - 1;
  int qi = qp / 14, qj = qp - qi * 14;
  int ki = kp / 14, kj = kp - ki * 14;
  return (qi - ki + 13) * 27 + (qj - kj + 13);
}

__global__ __launch_bounds__(256) void build_bias(const float* __restrict__ rel_tab,
                                                  unsigned short* __restrict__ bt) {
  int kk = threadIdx.x;
  if (kk >= 224) return;
  int qq = blockIdx.x;       // 0..207
  int head = blockIdx.y;     // 0..15
  unsigned short v = 0;
  if (qq < 197 && kk < 197)
    v = f2bf(rel_tab[relidx(qq, kk) * 16 + head]);
  bt[((long)head * 208 + qq) * 224 + kk] = v;
}

// ---------------- fused attention per (b,h), low-LDS, table-bias ------------
__global__ __launch_bounds__(256) void attn_kernel(
    const unsigned short* __restrict__ qg, const unsigned short* __restrict__ kg,
    const unsigned short* __restrict__ vg, const unsigned short* __restrict__ bias_tab,
    unsigned short* __restrict__ og) {
  __shared__ __align__(16) unsigned short Vt[64][224];
  __shared__ __align__(16) unsigned short Ps[4][16][224];

  const int tid = threadIdx.x;
  const int bh = blockIdx.x;
  const int head = bh & 15;
  const int b = bh >> 4;
  const unsigned short* qp = qg + (long)bh * 197 * 64;
  const unsigned short* kp = kg + (long)bh * 197 * 64;
  const unsigned short* vp = vg + (long)bh * 197 * 64;
  const unsigned short* bt = bias_tab + (long)head * 208 * 224;

  {
    ushort4 z; z.x = 0; z.y = 0; z.z = 0; z.w = 0;
    for (int i = tid; i < 64 * 8; i += 256) {
      int row = i >> 3, j = i & 7;
      ((ushort4*)&Vt[row][192])[j] = z;
    }
    for (int i = tid; i < 4 * 16 * 4; i += 256) {
      int w = i >> 6, rr = (i >> 2) & 15, j = i & 3;
      ((ushort4*)&Ps[w][rr][208])[j] = z;
    }
  }
  __syncthreads();
  for (int i = tid; i < 197 * 8; i += 256) {
    int row = i >> 3, c8 = (i & 7) * 8;
    bf16x8 vv = *(const bf16x8*)(vp + row * 64 + c8);
    #pragma unroll
    for (int j = 0; j < 8; ++j) Vt[c8 + j][row] = (unsigned short)vv[j];
  }
  __syncthreads();

  const int wv = tid >> 6, lane = tid & 63;
  const int lcol = lane & 15;
  const int lk8 = (lane >> 4) * 8;
  const int lrow4 = (lane >> 4) * 4;

  for (int strip = wv; strip < 13; strip += 4) {
    bf16x8 aq[2];
    #pragma unroll
    for (int kk = 0; kk < 2; ++kk)
      aq[kk] = *(const bf16x8*)(qp + (strip * 16 + lcol) * 64 + kk * 32 + lk8);
    f32x4 s[13];
    #pragma unroll
    for (int kt = 0; kt < 13; ++kt) {
      f32x4 z = {};
      #pragma unroll
      for (int kk = 0; kk < 2; ++kk) {
        bf16x8 bk = *(const bf16x8*)(kp + (kt * 16 + lcol) * 64 + kk * 32 + lk8);
        z = __builtin_amdgcn_mfma_f32_16x16x32_bf16(aq[kk], bk, z, 0, 0, 0);
      }
      s[kt] = z;
    }
    #pragma unroll
    for (int kt = 0; kt < 13; ++kt) {
      int ktok = kt * 16 + lcol;
      if (ktok >= 197) {
        #pragma unroll
        for (int r = 0; r < 4; ++r) s[kt][r] = -1e30f;
      } else {
        #pragma unroll
        for (int r = 0; r < 4; ++r) {
          int qq = strip * 16 + lrow4 + r;
          unsigned int bu = bt[qq * 224 + ktok];
          s[kt][r] += __builtin_bit_cast(float, bu << 16);
        }
      }
    }
    #pragma unroll
    for (int r = 0; r < 4; ++r) {
      float m = s[0][r];
      #pragma unroll
      for (int kt = 1; kt < 13; ++kt) m = fmaxf(m, s[kt][r]);
      #pragma unroll
      for (int d = 1; d < 16; d <<= 1) m = fmaxf(m, __shfl_xor(m, d));
      float sum = 0.0f;
      #pragma unroll
      for (int kt = 0; kt < 13; ++kt) { float p = __expf(s[kt][r] - m); s[kt][r] = p; sum += p; }
      #pragma unroll
      for (int d = 1; d < 16; d <<= 1) sum += __shfl_xor(sum, d);
      float rinv = 1.0f / sum;
      #pragma unroll
      for (int kt = 0; kt < 13; ++kt) s[kt][r] *= rinv;
    }
    #pragma unroll
    for (int kt = 0; kt < 13; ++kt)
      #pragma unroll
      for (int r = 0; r < 4; ++r)
        Ps[wv][lrow4 + r][kt * 16 + lcol] = f2bf(s[kt][r]);
    #pragma unroll
    for (int dt = 0; dt < 4; ++dt) {
      f32x4 oacc = {};
      #pragma unroll
      for (int kc = 0; kc < 7; ++kc) {
        bf16x8 ap = *(const bf16x8*)(&Ps[wv][lcol][kc * 32 + lk8]);
        bf16x8 bv = *(const bf16x8*)(&Vt[dt * 16 + lcol][kc * 32 + lk8]);
        oacc = __builtin_amdgcn_mfma_f32_16x16x32_bf16(ap, bv, oacc, 0, 0, 0);
      }
      #pragma unroll
      for (int r = 0; r < 4; ++r) {
        int qq = strip * 16 + lrow4 + r;
        if (qq < 197)
          og[((long)b * 197 + qq) * 1024 + head * 64 + dt * 16 + lcol] = f2bf(oacc[r]);
      }
    }
  }
}

// ---------------- launch ----------------
extern "C" void kernel_launch(void* const* d_in, const int* in_sizes, int n_in,
                              void* d_out, int out_size, void* d_ws, size_t ws_size,
                              hipStream_t stream) {
  const float* x        = (const float*)d_in[0];
  const float* qkv_w    = (const float*)d_in[1];
  const float* q_bias   = (const float*)d_in[2];
  const float* v_bias   = (const float*)d_in[3];
  const float* rel_tab  = (const float*)d_in[4];
  const float* proj_w   = (const float*)d_in[5];
  const float* proj_b   = (const float*)d_in[6];
  const float* ln1_g    = (const float*)d_in[7];
  const float* ln1_b    = (const float*)d_in[8];
  const float* ln2_g    = (const float*)d_in[9];
  const float* ln2_b    = (const float*)d_in[10];
  const float* fc1_w    = (const float*)d_in[11];
  const float* fc1_b    = (const float*)d_in[12];
  const float* fc2_w    = (const float*)d_in[13];
  const float* fc2_b    = (const float*)d_in[14];
  float* out = (float*)d_out;
  char* ws = (char*)d_ws;

  const int M = 64 * 197;            // 12608
  const size_t MP = 12800;           // padded to 100*128
  const int RB = 100;                // M block rows (BM=128)

  size_t off = 0;
  auto take = [&](size_t bytes) { size_t o = off; off += (bytes + 255) & ~(size_t)255; return o; };
  size_t o_wqkv = take((size_t)3072 * 1024 * 2);
  size_t o_wproj = take((size_t)1024 * 1024 * 2);
  size_t o_wfc1 = take((size_t)4096 * 1024 * 2);
  size_t o_wfc2 = take((size_t)1024 * 4096 * 2);
  size_t o_big  = take(MP * 4096 * 2);          // h+q+k+v overlap g (fc1 out)
  size_t o_o    = take(MP * 1024 * 2);          // attn out, reused as h2
  size_t o_bias = take((size_t)16 * 208 * 224 * 2);

  unsigned short* wqkv = (unsigned short*)(ws + o_wqkv);
  unsigned short* wproj = (unsigned short*)(ws + o_wproj);
  unsigned short* wfc1 = (unsigned short*)(ws + o_wfc1);
  unsigned short* wfc2 = (unsigned short*)(ws + o_wfc2);
  unsigned short* h   = (unsigned short*)(ws + o_big);
  unsigned short* qb  = (unsigned short*)(ws + o_big + MP * 1024 * 2);
  unsigned short* kb  = qb + (size_t)64 * 16 * 197 * 64;
  unsigned short* vb  = kb + (size_t)64 * 16 * 197 * 64;
  unsigned short* g   = (unsigned short*)(ws + o_big);       // fc1 out (h,q,k,v dead)
  unsigned short* ob  = (unsigned short*)(ws + o_o);
  unsigned short* h2  = ob;                                   // reuse after proj
  unsigned short* btab = (unsigned short*)(ws + o_bias);
  float* x1 = out;                                            // residual-1 lives in d_out

  cvt_all<<<2048, 256, 0, stream>>>(qkv_w, wqkv, 3145728 / 4,
                                    proj_w, wproj, 1048576 / 4,
                                    fc1_w, wfc1, 4194304 / 4,
                                    fc2_w, wfc2, 4194304 / 4);

  build_bias<<<dim3(208, 16), 256, 0, stream>>>(rel_tab, btab);

  ln_kernel<<<M, 256, 0, stream>>>(x, ln1_g, ln1_b, h, M);

  gemm_s<0><<<RB * 24, 256, 32768, stream>>>(h, wqkv, M, 3072, 1024, 24,
      q_bias, v_bias, nullptr, qb, kb, vb, nullptr);

  attn_kernel<<<1024, 256, 0, stream>>>(qb, kb, vb, btab, ob);

  gemm_s<1><<<RB * 8, 256, 32768, stream>>>(ob, wproj, M, 1024, 1024, 8,
      proj_b, nullptr, x, nullptr, nullptr, nullptr, x1);

  ln_kernel<<<M, 256, 0, stream>>>(x1, ln2_g, ln2_b, h2, M);

  gemm_s<2><<<RB * 32, 256, 32768, stream>>>(h2, wfc1, M, 4096, 1024, 32,
      fc1_b, nullptr, nullptr, g, nullptr, nullptr, nullptr);

  gemm_s<3><<<RB * 8, 256, 32768, stream>>>(g, wfc2, M, 1024, 4096, 8,
      fc2_b, nullptr, x1, nullptr, nullptr, nullptr, out);
}

// Round 7
// 533.883 us; speedup vs baseline: 1.1227x; 1.1227x over previous
//
#include <hip/hip_runtime.h>
#include <hip/hip_bf16.h>
#include <cstdint>

typedef __attribute__((ext_vector_type(8))) short bf16x8;   // 8 bf16 bit-patterns
typedef __attribute__((ext_vector_type(4))) float f32x4;

#define AS1 __attribute__((address_space(1)))
#define AS3 __attribute__((address_space(3)))

__device__ __forceinline__ void gload16(const void* g, void* l) {
  __builtin_amdgcn_global_load_lds((const AS1 unsigned int*)g,
                                   (AS3 unsigned int*)l, 16, 0, 0);
}

__device__ __forceinline__ unsigned short f2bf(float f) {
  unsigned int u = __builtin_bit_cast(unsigned int, f);
  u += 0x7FFFu + ((u >> 16) & 1u);           // RNE
  return (unsigned short)(u >> 16);
}

// exact-erf GELU via Abramowitz-Stegun 7.1.26 (|erf err| <= 1.5e-7), branch-free
__device__ __forceinline__ float fast_gelu(float x) {
  float z = fabsf(x) * 0.70710678118654752f;
  float t = __builtin_amdgcn_rcpf(1.0f + 0.3275911f * z);
  float poly = t * (0.254829592f + t * (-0.284496736f + t * (1.421413741f +
               t * (-1.453152027f + t * 1.061405429f))));
  float erf_abs = 1.0f - poly * __expf(-z * z);
  float erfv = (x < 0.0f) ? -erf_abs : erf_abs;
  return 0.5f * x * (1.0f + erfv);
}

// ---------------- fused fp32 -> bf16 convert (all 4 weights, 1 launch) -------
__global__ __launch_bounds__(256) void cvt_all(
    const float* __restrict__ s0, unsigned short* __restrict__ d0, int n0,
    const float* __restrict__ s1, unsigned short* __restrict__ d1, int n1,
    const float* __restrict__ s2, unsigned short* __restrict__ d2, int n2,
    const float* __restrict__ s3, unsigned short* __restrict__ d3, int n3) {
  int total = n0 + n1 + n2 + n3;
  int stride = gridDim.x * 256;
  for (int i = blockIdx.x * 256 + threadIdx.x; i < total; i += stride) {
    const float* s; unsigned short* d; int j = i;
    if (j < n0) { s = s0; d = d0; }
    else if ((j -= n0) < n1) { s = s1; d = d1; }
    else if ((j -= n1) < n2) { s = s2; d = d2; }
    else { j -= n2; s = s3; d = d3; }
    float4 v = ((const float4*)s)[j];
    ushort4 st;
    st.x = f2bf(v.x); st.y = f2bf(v.y); st.z = f2bf(v.z); st.w = f2bf(v.w);
    ((ushort4*)d)[j] = st;
  }
}

// ---------------- LayerNorm (row=1024) -> bf16 ----------------
__global__ __launch_bounds__(256) void ln_kernel(const float* __restrict__ x,
                                                 const float* __restrict__ gw,
                                                 const float* __restrict__ bw,
                                                 unsigned short* __restrict__ out,
                                                 int rows) {
  int row = blockIdx.x;
  if (row >= rows) return;
  const float4* xr = (const float4*)(x + (size_t)row * 1024);
  int tid = threadIdx.x;
  float4 v = xr[tid];
  float s = v.x + v.y + v.z + v.w;
  float s2 = v.x * v.x + v.y * v.y + v.z * v.z + v.w * v.w;
  #pragma unroll
  for (int m = 1; m < 64; m <<= 1) { s += __shfl_xor(s, m); s2 += __shfl_xor(s2, m); }
  __shared__ float ls[4], ls2[4];
  int wv = tid >> 6;
  if ((tid & 63) == 0) { ls[wv] = s; ls2[wv] = s2; }
  __syncthreads();
  s = ls[0] + ls[1] + ls[2] + ls[3];
  s2 = ls2[0] + ls2[1] + ls2[2] + ls2[3];
  float mu = s * (1.0f / 1024.0f);
  float var = s2 * (1.0f / 1024.0f) - mu * mu;
  float rs = rsqrtf(var + 1e-5f);
  float4 g4 = ((const float4*)gw)[tid];
  float4 b4 = ((const float4*)bw)[tid];
  ushort4 st;
  st.x = f2bf((v.x - mu) * rs * g4.x + b4.x);
  st.y = f2bf((v.y - mu) * rs * g4.y + b4.y);
  st.z = f2bf((v.z - mu) * rs * g4.z + b4.z);
  st.w = f2bf((v.w - mu) * rs * g4.w + b4.w);
  ((ushort4*)(out + (size_t)row * 1024))[tid] = st;
}

// ---------------- 128x256 BK=32 B^T GEMM, col-fastest L2 blocking -----------
template<int EPI>
__global__ __launch_bounds__(512) void gemm_f(
    const unsigned short* __restrict__ A, const unsigned short* __restrict__ B,
    int M, int N, int K, int CP,
    const float* __restrict__ bias0, const float* __restrict__ bias1,
    const float* __restrict__ resid,
    unsigned short* __restrict__ o0, unsigned short* __restrict__ o1,
    unsigned short* __restrict__ o2, float* __restrict__ f_out) {
  extern __shared__ unsigned short smem[];   // 24576 ushorts = 48 KiB
  const int tid = threadIdx.x;
  const int lane = tid & 63;
  const int wid = tid >> 6;
  const int wr = wid >> 2;        // 0..1 (M half, 64 rows)
  const int wc = wid & 3;         // 0..3 (N quarter, 64 cols)
  const int lane15 = lane & 15, l16 = lane >> 4;

  const int nwg = gridDim.x;
  const int bid = blockIdx.x;
  const int q = nwg >> 3, rmd = nwg & 7;
  const int xcd = bid & 7, idx = bid >> 3;
  const int s = (xcd < rmd ? xcd * (q + 1) : rmd * (q + 1) + (xcd - rmd) * q) + idx;
  const int brow = s / CP, bcol = s - brow * CP;
  const long row0 = (long)brow * 128;
  const long col0 = (long)bcol * 256;
  const int NT = K >> 5;

  const int srow = tid >> 2;                 // 0..127
  const int scol = (tid & 3) * 8;            // element col within 32-elem row
  const int sdst = tid << 3;                 // ushort offset (linear)

  auto stageAll = [&](int t) {
    const int buf = t & 1;
    const long kofs = (long)t * 32 + scol;
    gload16(A + (row0 + srow) * (long)K + kofs, smem + buf * 4096 + sdst);
    unsigned short* Bd = smem + 8192 + buf * 8192 + sdst;
    gload16(B + (col0 + srow) * (long)K + kofs, Bd);
    gload16(B + (col0 + 128 + srow) * (long)K + kofs, Bd + 4096);
  };

  f32x4 acc[4][4] = {};

  stageAll(0);

  for (int t = 0; t < NT; ++t) {
    if (t + 1 < NT) { stageAll(t + 1);
                      asm volatile("s_waitcnt vmcnt(3)" ::: "memory"); }
    else            { asm volatile("s_waitcnt vmcnt(0)" ::: "memory"); }
    __builtin_amdgcn_s_barrier();

    const unsigned short* Acur = smem + (t & 1) * 4096;
    const unsigned short* Bcur = smem + 8192 + (t & 1) * 8192;
    bf16x8 afrag[4], bfrag[4];
    #pragma unroll
    for (int mi = 0; mi < 4; ++mi)
      afrag[mi] = *(const bf16x8*)(Acur + (wr * 64 + mi * 16 + lane15) * 32 + l16 * 8);
    #pragma unroll
    for (int ni = 0; ni < 4; ++ni)
      bfrag[ni] = *(const bf16x8*)(Bcur + (wc * 64 + ni * 16 + lane15) * 32 + l16 * 8);
    asm volatile("s_waitcnt lgkmcnt(0)" ::: "memory");
    __builtin_amdgcn_sched_barrier(0);
    __builtin_amdgcn_s_setprio(1);
    #pragma unroll
    for (int mi = 0; mi < 4; ++mi)
      #pragma unroll
      for (int ni = 0; ni < 4; ++ni)
        acc[mi][ni] = __builtin_amdgcn_mfma_f32_16x16x32_bf16(
            afrag[mi], bfrag[ni], acc[mi][ni], 0, 0, 0);
    __builtin_amdgcn_s_setprio(0);
    __builtin_amdgcn_s_barrier();
  }

  // ---------------- epilogue ----------------
  const int lrow = l16 * 4;
  if constexpr (EPI == 0) {
    const int colbase = (int)col0 + wc * 64;
    const int part = colbase >> 10;
    const int hd0 = colbase & 1023;
    const int head = hd0 >> 6;
    unsigned short* dst = (part == 0) ? o0 : (part == 1 ? o1 : o2);
    const float scl = (part == 0) ? 0.125f : 1.0f;
    float bias[4];
    #pragma unroll
    for (int ni = 0; ni < 4; ++ni) {
      int hd = hd0 + ni * 16 + lane15;
      bias[ni] = (part == 0) ? bias0[hd] : (part == 2 ? bias1[hd] : 0.0f);
    }
    #pragma unroll
    for (int mi = 0; mi < 4; ++mi) {
      #pragma unroll
      for (int r = 0; r < 4; ++r) {
        int irow = (int)row0 + wr * 64 + mi * 16 + lrow + r;
        if (irow >= M) continue;
        int bb = irow / 197, tk = irow - bb * 197;
        long obase = ((long)(bb * 16 + head) * 197 + tk) * 64;
        #pragma unroll
        for (int ni = 0; ni < 4; ++ni)
          dst[obase + ni * 16 + lane15] = f2bf((acc[mi][ni][r] + bias[ni]) * scl);
      }
    }
  } else {
    float bias[4];
    #pragma unroll
    for (int ni = 0; ni < 4; ++ni)
      bias[ni] = bias0[col0 + wc * 64 + ni * 16 + lane15];
    #pragma unroll
    for (int mi = 0; mi < 4; ++mi) {
      #pragma unroll
      for (int r = 0; r < 4; ++r) {
        long row = row0 + wr * 64 + mi * 16 + lrow + r;
        if (row >= M) continue;
        long cbase = col0 + wc * 64 + lane15;
        #pragma unroll
        for (int ni = 0; ni < 4; ++ni) {
          long col = cbase + ni * 16;
          float cv = acc[mi][ni][r] + bias[ni];
          if constexpr (EPI == 2) {
            o0[row * (long)N + col] = f2bf(fast_gelu(cv));
          } else {
            f_out[row * 1024 + col] = cv + resid[row * 1024 + col];
          }
        }
      }
    }
  }
}

// ---------------- rel-pos bias table build: bt[16][208][224] bf16 ------------
__device__ __forceinline__ int relidx(int q, int k) {
  if (q == 0) return (k == 0) ? 731 : 729;
  if (k == 0) return 730;
  int qp = q - 1, kp = k - 1;
  int qi = qp / 14, qj = qp - qi * 14;
  int ki = kp / 14, kj = kp - ki * 14;
  return (qi - ki + 13) * 27 + (qj - kj + 13);
}

__global__ __launch_bounds__(256) void build_bias(const float* __restrict__ rel_tab,
                                                  unsigned short* __restrict__ bt) {
  int kk = threadIdx.x;
  if (kk >= 224) return;
  int qq = blockIdx.x;       // 0..207
  int head = blockIdx.y;     // 0..15
  unsigned short v = 0;
  if (qq < 197 && kk < 197)
    v = f2bf(rel_tab[relidx(qq, kk) * 16 + head]);
  bt[((long)head * 208 + qq) * 224 + kk] = v;
}

// ---------------- fused attention per (b,h), low-LDS, table-bias ------------
// Q/K fragments direct from global (L2-hot). V^T + per-wave P in LDS (~60 KB,
// 2 blocks/CU). Bias added via coalesced bf16 table loads. PV loop hoists the
// dt-invariant P fragments (7 reads instead of 28).
__global__ __launch_bounds__(256) void attn_kernel(
    const unsigned short* __restrict__ qg, const unsigned short* __restrict__ kg,
    const unsigned short* __restrict__ vg, const unsigned short* __restrict__ bias_tab,
    unsigned short* __restrict__ og) {
  __shared__ __align__(16) unsigned short Vt[64][224];
  __shared__ __align__(16) unsigned short Ps[4][16][224];

  const int tid = threadIdx.x;
  const int bh = blockIdx.x;
  const int head = bh & 15;
  const int b = bh >> 4;
  const unsigned short* qp = qg + (long)bh * 197 * 64;
  const unsigned short* kp = kg + (long)bh * 197 * 64;
  const unsigned short* vp = vg + (long)bh * 197 * 64;
  const unsigned short* bt = bias_tab + (long)head * 208 * 224;

  {
    ushort4 z; z.x = 0; z.y = 0; z.z = 0; z.w = 0;
    for (int i = tid; i < 64 * 8; i += 256) {        // 64 rows x 8 ushort4 (cols 192..223)
      int row = i >> 3, j = i & 7;
      ((ushort4*)&Vt[row][192])[j] = z;
    }
    for (int i = tid; i < 4 * 16 * 4; i += 256) {    // 4 waves x 16 rows x 4 ushort4 (cols 208..223)
      int w = i >> 6, rr = (i >> 2) & 15, j = i & 3;
      ((ushort4*)&Ps[w][rr][208])[j] = z;
    }
  }
  __syncthreads();
  // V transpose into LDS
  for (int i = tid; i < 197 * 8; i += 256) {
    int row = i >> 3, c8 = (i & 7) * 8;
    bf16x8 vv = *(const bf16x8*)(vp + row * 64 + c8);
    #pragma unroll
    for (int j = 0; j < 8; ++j) Vt[c8 + j][row] = (unsigned short)vv[j];
  }
  __syncthreads();

  const int wv = tid >> 6, lane = tid & 63;
  const int lcol = lane & 15;
  const int lk8 = (lane >> 4) * 8;
  const int lrow4 = (lane >> 4) * 4;

  for (int strip = wv; strip < 13; strip += 4) {
    bf16x8 aq[2];
    #pragma unroll
    for (int kk = 0; kk < 2; ++kk)
      aq[kk] = *(const bf16x8*)(qp + (strip * 16 + lcol) * 64 + kk * 32 + lk8);
    f32x4 s[13];
    #pragma unroll
    for (int kt = 0; kt < 13; ++kt) {
      f32x4 z = {};
      #pragma unroll
      for (int kk = 0; kk < 2; ++kk) {
        bf16x8 bk = *(const bf16x8*)(kp + (kt * 16 + lcol) * 64 + kk * 32 + lk8);
        z = __builtin_amdgcn_mfma_f32_16x16x32_bf16(aq[kk], bk, z, 0, 0, 0);
      }
      s[kt] = z;
    }
    // bias add from table (coalesced 2B loads) + k mask
    #pragma unroll
    for (int kt = 0; kt < 13; ++kt) {
      int ktok = kt * 16 + lcol;
      if (ktok >= 197) {
        #pragma unroll
        for (int r = 0; r < 4; ++r) s[kt][r] = -1e30f;
      } else {
        #pragma unroll
        for (int r = 0; r < 4; ++r) {
          int qq = strip * 16 + lrow4 + r;          // <= 207, table-padded
          unsigned int bu = bt[qq * 224 + ktok];
          s[kt][r] += __builtin_bit_cast(float, bu << 16);
        }
      }
    }
    #pragma unroll
    for (int r = 0; r < 4; ++r) {
      float m = s[0][r];
      #pragma unroll
      for (int kt = 1; kt < 13; ++kt) m = fmaxf(m, s[kt][r]);
      #pragma unroll
      for (int d = 1; d < 16; d <<= 1) m = fmaxf(m, __shfl_xor(m, d));
      float sum = 0.0f;
      #pragma unroll
      for (int kt = 0; kt < 13; ++kt) { float p = __expf(s[kt][r] - m); s[kt][r] = p; sum += p; }
      #pragma unroll
      for (int d = 1; d < 16; d <<= 1) sum += __shfl_xor(sum, d);
      float rinv = 1.0f / sum;
      #pragma unroll
      for (int kt = 0; kt < 13; ++kt) s[kt][r] *= rinv;
    }
    #pragma unroll
    for (int kt = 0; kt < 13; ++kt)
      #pragma unroll
      for (int r = 0; r < 4; ++r)
        Ps[wv][lrow4 + r][kt * 16 + lcol] = f2bf(s[kt][r]);
    bf16x8 pa[7];
    #pragma unroll
    for (int kc = 0; kc < 7; ++kc)
      pa[kc] = *(const bf16x8*)(&Ps[wv][lcol][kc * 32 + lk8]);
    #pragma unroll
    for (int dt = 0; dt < 4; ++dt) {
      f32x4 oacc = {};
      #pragma unroll
      for (int kc = 0; kc < 7; ++kc) {
        bf16x8 bv = *(const bf16x8*)(&Vt[dt * 16 + lcol][kc * 32 + lk8]);
        oacc = __builtin_amdgcn_mfma_f32_16x16x32_bf16(pa[kc], bv, oacc, 0, 0, 0);
      }
      #pragma unroll
      for (int r = 0; r < 4; ++r) {
        int qq = strip * 16 + lrow4 + r;
        if (qq < 197)
          og[((long)b * 197 + qq) * 1024 + head * 64 + dt * 16 + lcol] = f2bf(oacc[r]);
      }
    }
  }
}

// ---------------- launch ----------------
extern "C" void kernel_launch(void* const* d_in, const int* in_sizes, int n_in,
                              void* d_out, int out_size, void* d_ws, size_t ws_size,
                              hipStream_t stream) {
  const float* x        = (const float*)d_in[0];
  const float* qkv_w    = (const float*)d_in[1];
  const float* q_bias   = (const float*)d_in[2];
  const float* v_bias   = (const float*)d_in[3];
  const float* rel_tab  = (const float*)d_in[4];
  const float* proj_w   = (const float*)d_in[5];
  const float* proj_b   = (const float*)d_in[6];
  const float* ln1_g    = (const float*)d_in[7];
  const float* ln1_b    = (const float*)d_in[8];
  const float* ln2_g    = (const float*)d_in[9];
  const float* ln2_b    = (const float*)d_in[10];
  const float* fc1_w    = (const float*)d_in[11];
  const float* fc1_b    = (const float*)d_in[12];
  const float* fc2_w    = (const float*)d_in[13];
  const float* fc2_b    = (const float*)d_in[14];
  float* out = (float*)d_out;
  char* ws = (char*)d_ws;

  const int M = 64 * 197;            // 12608
  const size_t MP = 12800;           // padded to 100*128
  const int RB = 100;                // M block rows (BM=128)

  size_t off = 0;
  auto take = [&](size_t bytes) { size_t o = off; off += (bytes + 255) & ~(size_t)255; return o; };
  size_t o_wqkv = take((size_t)3072 * 1024 * 2);
  size_t o_wproj = take((size_t)1024 * 1024 * 2);
  size_t o_wfc1 = take((size_t)4096 * 1024 * 2);
  size_t o_wfc2 = take((size_t)1024 * 4096 * 2);
  size_t o_big  = take(MP * 4096 * 2);          // h+q+k+v overlap g (fc1 out)
  size_t o_o    = take(MP * 1024 * 2);          // attn out, reused as h2
  size_t o_bias = take((size_t)16 * 208 * 224 * 2);

  unsigned short* wqkv = (unsigned short*)(ws + o_wqkv);
  unsigned short* wproj = (unsigned short*)(ws + o_wproj);
  unsigned short* wfc1 = (unsigned short*)(ws + o_wfc1);
  unsigned short* wfc2 = (unsigned short*)(ws + o_wfc2);
  unsigned short* h   = (unsigned short*)(ws + o_big);
  unsigned short* qb  = (unsigned short*)(ws + o_big + MP * 1024 * 2);
  unsigned short* kb  = qb + (size_t)64 * 16 * 197 * 64;
  unsigned short* vb  = kb + (size_t)64 * 16 * 197 * 64;
  unsigned short* g   = (unsigned short*)(ws + o_big);       // fc1 out (h,q,k,v dead)
  unsigned short* ob  = (unsigned short*)(ws + o_o);
  unsigned short* h2  = ob;                                   // reuse after proj
  unsigned short* btab = (unsigned short*)(ws + o_bias);
  float* x1 = out;                                            // residual-1 lives in d_out

  cvt_all<<<2048, 256, 0, stream>>>(qkv_w, wqkv, 3145728 / 4,
                                    proj_w, wproj, 1048576 / 4,
                                    fc1_w, wfc1, 4194304 / 4,
                                    fc2_w, wfc2, 4194304 / 4);

  build_bias<<<dim3(208, 16), 256, 0, stream>>>(rel_tab, btab);

  ln_kernel<<<M, 256, 0, stream>>>(x, ln1_g, ln1_b, h, M);

  gemm_f<0><<<RB * 12, 512, 49152, stream>>>(h, wqkv, M, 3072, 1024, 12,
      q_bias, v_bias, nullptr, qb, kb, vb, nullptr);

  attn_kernel<<<1024, 256, 0, stream>>>(qb, kb, vb, btab, ob);

  gemm_f<1><<<RB * 4, 512, 49152, stream>>>(ob, wproj, M, 1024, 1024, 4,
      proj_b, nullptr, x, nullptr, nullptr, nullptr, x1);

  ln_kernel<<<M, 256, 0, stream>>>(x1, ln2_g, ln2_b, h2, M);

  gemm_f<2><<<RB * 16, 512, 49152, stream>>>(h2, wfc1, M, 4096, 1024, 16,
      fc1_b, nullptr, nullptr, g, nullptr, nullptr, nullptr);

  gemm_f<3><<<RB * 4, 512, 49152, stream>>>(g, wfc2, M, 1024, 4096, 4,
      fc2_b, nullptr, x1, nullptr, nullptr, nullptr, out);
}

// Round 8
// 531.654 us; speedup vs baseline: 1.1274x; 1.0042x over previous
//
#include <hip/hip_runtime.h>
#include <hip/hip_bf16.h>
#include <cstdint>

typedef __attribute__((ext_vector_type(8))) short bf16x8;   // 8 bf16 bit-patterns
typedef __attribute__((ext_vector_type(4))) float f32x4;

#define AS1 __attribute__((address_space(1)))
#define AS3 __attribute__((address_space(3)))

__device__ __forceinline__ void gload16(const void* g, void* l) {
  __builtin_amdgcn_global_load_lds((const AS1 unsigned int*)g,
                                   (AS3 unsigned int*)l, 16, 0, 0);
}

__device__ __forceinline__ unsigned short f2bf(float f) {
  unsigned int u = __builtin_bit_cast(unsigned int, f);
  u += 0x7FFFu + ((u >> 16) & 1u);           // RNE
  return (unsigned short)(u >> 16);
}

// exact-erf GELU via Abramowitz-Stegun 7.1.26 (|erf err| <= 1.5e-7), branch-free
__device__ __forceinline__ float fast_gelu(float x) {
  float z = fabsf(x) * 0.70710678118654752f;
  float t = __builtin_amdgcn_rcpf(1.0f + 0.3275911f * z);
  float poly = t * (0.254829592f + t * (-0.284496736f + t * (1.421413741f +
               t * (-1.453152027f + t * 1.061405429f))));
  float erf_abs = 1.0f - poly * __expf(-z * z);
  float erfv = (x < 0.0f) ? -erf_abs : erf_abs;
  return 0.5f * x * (1.0f + erfv);
}

// ---------------- fused fp32 -> bf16 convert (all 4 weights, 1 launch) -------
__global__ __launch_bounds__(256) void cvt_all(
    const float* __restrict__ s0, unsigned short* __restrict__ d0, int n0,
    const float* __restrict__ s1, unsigned short* __restrict__ d1, int n1,
    const float* __restrict__ s2, unsigned short* __restrict__ d2, int n2,
    const float* __restrict__ s3, unsigned short* __restrict__ d3, int n3) {
  int total = n0 + n1 + n2 + n3;
  int stride = gridDim.x * 256;
  for (int i = blockIdx.x * 256 + threadIdx.x; i < total; i += stride) {
    const float* s; unsigned short* d; int j = i;
    if (j < n0) { s = s0; d = d0; }
    else if ((j -= n0) < n1) { s = s1; d = d1; }
    else if ((j -= n1) < n2) { s = s2; d = d2; }
    else { j -= n2; s = s3; d = d3; }
    float4 v = ((const float4*)s)[j];
    ushort4 st;
    st.x = f2bf(v.x); st.y = f2bf(v.y); st.z = f2bf(v.z); st.w = f2bf(v.w);
    ((ushort4*)d)[j] = st;
  }
}

// ---------------- LayerNorm (row=1024) -> bf16 ----------------
__global__ __launch_bounds__(256) void ln_kernel(const float* __restrict__ x,
                                                 const float* __restrict__ gw,
                                                 const float* __restrict__ bw,
                                                 unsigned short* __restrict__ out,
                                                 int rows) {
  int row = blockIdx.x;
  if (row >= rows) return;
  const float4* xr = (const float4*)(x + (size_t)row * 1024);
  int tid = threadIdx.x;
  float4 v = xr[tid];
  float s = v.x + v.y + v.z + v.w;
  float s2 = v.x * v.x + v.y * v.y + v.z * v.z + v.w * v.w;
  #pragma unroll
  for (int m = 1; m < 64; m <<= 1) { s += __shfl_xor(s, m); s2 += __shfl_xor(s2, m); }
  __shared__ float ls[4], ls2[4];
  int wv = tid >> 6;
  if ((tid & 63) == 0) { ls[wv] = s; ls2[wv] = s2; }
  __syncthreads();
  s = ls[0] + ls[1] + ls[2] + ls[3];
  s2 = ls2[0] + ls2[1] + ls2[2] + ls2[3];
  float mu = s * (1.0f / 1024.0f);
  float var = s2 * (1.0f / 1024.0f) - mu * mu;
  float rs = rsqrtf(var + 1e-5f);
  float4 g4 = ((const float4*)gw)[tid];
  float4 b4 = ((const float4*)bw)[tid];
  ushort4 st;
  st.x = f2bf((v.x - mu) * rs * g4.x + b4.x);
  st.y = f2bf((v.y - mu) * rs * g4.y + b4.y);
  st.z = f2bf((v.z - mu) * rs * g4.z + b4.z);
  st.w = f2bf((v.w - mu) * rs * g4.w + b4.w);
  ((ushort4*)(out + (size_t)row * 1024))[tid] = st;
}

// ---------------- 128x256 BK=32 B^T GEMM + 16B-slot XOR swizzle -------------
// Round-0 proven schedule, ONE change: bank swizzle slot' = slot ^ ((row>>1)&3)
// applied BOTH sides (pre-swizzled global source since global_load_lds writes
// linearly; XOR folded into the per-thread read constant swl — zero loop VALU).
// Derivation: unswizzled 16-lane frag read spans 16 rows @64B stride, one 16B
// slot -> bank base 16*(r&1), 8 lanes/bank-set = 8-way conflict. With XOR,
// (r&1, slot^((r>>1)&3)) takes 8 distinct bank-sets over 8 rows -> 2-way=free.
template<int EPI>
__global__ __launch_bounds__(512) void gemm_f(
    const unsigned short* __restrict__ A, const unsigned short* __restrict__ B,
    int M, int N, int K, int CP,
    const float* __restrict__ bias0, const float* __restrict__ bias1,
    const float* __restrict__ resid,
    unsigned short* __restrict__ o0, unsigned short* __restrict__ o1,
    unsigned short* __restrict__ o2, float* __restrict__ f_out) {
  extern __shared__ unsigned short smem[];   // 24576 ushorts = 48 KiB
  const int tid = threadIdx.x;
  const int lane = tid & 63;
  const int wid = tid >> 6;
  const int wr = wid >> 2;        // 0..1 (M half, 64 rows)
  const int wc = wid & 3;         // 0..3 (N quarter, 64 cols)
  const int lane15 = lane & 15, l16 = lane >> 4;
  const int swl = l16 ^ ((lane15 >> 1) & 3);   // swizzled slot (per-thread const)

  const int nwg = gridDim.x;
  const int bid = blockIdx.x;
  const int q = nwg >> 3, rmd = nwg & 7;
  const int xcd = bid & 7, idx = bid >> 3;
  const int s = (xcd < rmd ? xcd * (q + 1) : rmd * (q + 1) + (xcd - rmd) * q) + idx;
  const int brow = s / CP, bcol = s - brow * CP;
  const long row0 = (long)brow * 128;
  const long col0 = (long)bcol * 256;
  const int NT = K >> 5;

  const int srow = tid >> 2;                 // 0..127
  const int scol = ((tid & 3) ^ ((srow >> 1) & 3)) * 8;  // pre-swizzled source col
  const int sdst = tid << 3;                 // ushort offset (linear dest)

  auto stageAll = [&](int t) {
    const int buf = t & 1;
    const long kofs = (long)t * 32 + scol;
    gload16(A + (row0 + srow) * (long)K + kofs, smem + buf * 4096 + sdst);
    unsigned short* Bd = smem + 8192 + buf * 8192 + sdst;
    gload16(B + (col0 + srow) * (long)K + kofs, Bd);
    gload16(B + (col0 + 128 + srow) * (long)K + kofs, Bd + 4096);
  };

  f32x4 acc[4][4] = {};

  stageAll(0);

  for (int t = 0; t < NT; ++t) {
    if (t + 1 < NT) { stageAll(t + 1);
                      asm volatile("s_waitcnt vmcnt(3)" ::: "memory"); }
    else            { asm volatile("s_waitcnt vmcnt(0)" ::: "memory"); }
    __builtin_amdgcn_s_barrier();

    const unsigned short* Acur = smem + (t & 1) * 4096;
    const unsigned short* Bcur = smem + 8192 + (t & 1) * 8192;
    bf16x8 afrag[4], bfrag[4];
    #pragma unroll
    for (int mi = 0; mi < 4; ++mi)
      afrag[mi] = *(const bf16x8*)(Acur + (wr * 64 + mi * 16 + lane15) * 32 + swl * 8);
    #pragma unroll
    for (int ni = 0; ni < 4; ++ni)
      bfrag[ni] = *(const bf16x8*)(Bcur + (wc * 64 + ni * 16 + lane15) * 32 + swl * 8);
    asm volatile("s_waitcnt lgkmcnt(0)" ::: "memory");
    __builtin_amdgcn_sched_barrier(0);
    __builtin_amdgcn_s_setprio(1);
    #pragma unroll
    for (int mi = 0; mi < 4; ++mi)
      #pragma unroll
      for (int ni = 0; ni < 4; ++ni)
        acc[mi][ni] = __builtin_amdgcn_mfma_f32_16x16x32_bf16(
            afrag[mi], bfrag[ni], acc[mi][ni], 0, 0, 0);
    __builtin_amdgcn_s_setprio(0);
    __builtin_amdgcn_s_barrier();
  }

  // ---------------- epilogue ----------------
  const int lrow = l16 * 4;
  if constexpr (EPI == 0) {
    const int colbase = (int)col0 + wc * 64;
    const int part = colbase >> 10;
    const int hd0 = colbase & 1023;
    const int head = hd0 >> 6;
    unsigned short* dst = (part == 0) ? o0 : (part == 1 ? o1 : o2);
    const float scl = (part == 0) ? 0.125f : 1.0f;
    float bias[4];
    #pragma unroll
    for (int ni = 0; ni < 4; ++ni) {
      int hd = hd0 + ni * 16 + lane15;
      bias[ni] = (part == 0) ? bias0[hd] : (part == 2 ? bias1[hd] : 0.0f);
    }
    #pragma unroll
    for (int mi = 0; mi < 4; ++mi) {
      #pragma unroll
      for (int r = 0; r < 4; ++r) {
        int irow = (int)row0 + wr * 64 + mi * 16 + lrow + r;
        if (irow >= M) continue;
        int bb = irow / 197, tk = irow - bb * 197;
        long obase = ((long)(bb * 16 + head) * 197 + tk) * 64;
        #pragma unroll
        for (int ni = 0; ni < 4; ++ni)
          dst[obase + ni * 16 + lane15] = f2bf((acc[mi][ni][r] + bias[ni]) * scl);
      }
    }
  } else {
    float bias[4];
    #pragma unroll
    for (int ni = 0; ni < 4; ++ni)
      bias[ni] = bias0[col0 + wc * 64 + ni * 16 + lane15];
    #pragma unroll
    for (int mi = 0; mi < 4; ++mi) {
      #pragma unroll
      for (int r = 0; r < 4; ++r) {
        long row = row0 + wr * 64 + mi * 16 + lrow + r;
        if (row >= M) continue;
        long cbase = col0 + wc * 64 + lane15;
        #pragma unroll
        for (int ni = 0; ni < 4; ++ni) {
          long col = cbase + ni * 16;
          float cv = acc[mi][ni][r] + bias[ni];
          if constexpr (EPI == 2) {
            o0[row * (long)N + col] = f2bf(fast_gelu(cv));
          } else {
            f_out[row * 1024 + col] = cv + resid[row * 1024 + col];
          }
        }
      }
    }
  }
}

// ---------------- rel-pos bias table build: bt[16][208][224] bf16 ------------
__device__ __forceinline__ int relidx(int q, int k) {
  if (q == 0) return (k == 0) ? 731 : 729;
  if (k == 0) return 730;
  int qp = q - 1, kp = k - 1;
  int qi = qp / 14, qj = qp - qi * 14;
  int ki = kp / 14, kj = kp - ki * 14;
  return (qi - ki + 13) * 27 + (qj - kj + 13);
}

__global__ __launch_bounds__(256) void build_bias(const float* __restrict__ rel_tab,
                                                  unsigned short* __restrict__ bt) {
  int kk = threadIdx.x;
  if (kk >= 224) return;
  int qq = blockIdx.x;       // 0..207
  int head = blockIdx.y;     // 0..15
  unsigned short v = 0;
  if (qq < 197 && kk < 197)
    v = f2bf(rel_tab[relidx(qq, kk) * 16 + head]);
  bt[((long)head * 208 + qq) * 224 + kk] = v;
}

// ---------------- fused attention per (b,h), low-LDS, table-bias ------------
__global__ __launch_bounds__(256) void attn_kernel(
    const unsigned short* __restrict__ qg, const unsigned short* __restrict__ kg,
    const unsigned short* __restrict__ vg, const unsigned short* __restrict__ bias_tab,
    unsigned short* __restrict__ og) {
  __shared__ __align__(16) unsigned short Vt[64][224];
  __shared__ __align__(16) unsigned short Ps[4][16][224];

  const int tid = threadIdx.x;
  const int bh = blockIdx.x;
  const int head = bh & 15;
  const int b = bh >> 4;
  const unsigned short* qp = qg + (long)bh * 197 * 64;
  const unsigned short* kp = kg + (long)bh * 197 * 64;
  const unsigned short* vp = vg + (long)bh * 197 * 64;
  const unsigned short* bt = bias_tab + (long)head * 208 * 224;

  {
    ushort4 z; z.x = 0; z.y = 0; z.z = 0; z.w = 0;
    for (int i = tid; i < 64 * 8; i += 256) {
      int row = i >> 3, j = i & 7;
      ((ushort4*)&Vt[row][192])[j] = z;
    }
    for (int i = tid; i < 4 * 16 * 4; i += 256) {
      int w = i >> 6, rr = (i >> 2) & 15, j = i & 3;
      ((ushort4*)&Ps[w][rr][208])[j] = z;
    }
  }
  __syncthreads();
  for (int i = tid; i < 197 * 8; i += 256) {
    int row = i >> 3, c8 = (i & 7) * 8;
    bf16x8 vv = *(const bf16x8*)(vp + row * 64 + c8);
    #pragma unroll
    for (int j = 0; j < 8; ++j) Vt[c8 + j][row] = (unsigned short)vv[j];
  }
  __syncthreads();

  const int wv = tid >> 6, lane = tid & 63;
  const int lcol = lane & 15;
  const int lk8 = (lane >> 4) * 8;
  const int lrow4 = (lane >> 4) * 4;

  for (int strip = wv; strip < 13; strip += 4) {
    bf16x8 aq[2];
    #pragma unroll
    for (int kk = 0; kk < 2; ++kk)
      aq[kk] = *(const bf16x8*)(qp + (strip * 16 + lcol) * 64 + kk * 32 + lk8);
    f32x4 s[13];
    #pragma unroll
    for (int kt = 0; kt < 13; ++kt) {
      f32x4 z = {};
      #pragma unroll
      for (int kk = 0; kk < 2; ++kk) {
        bf16x8 bk = *(const bf16x8*)(kp + (kt * 16 + lcol) * 64 + kk * 32 + lk8);
        z = __builtin_amdgcn_mfma_f32_16x16x32_bf16(aq[kk], bk, z, 0, 0, 0);
      }
      s[kt] = z;
    }
    #pragma unroll
    for (int kt = 0; kt < 13; ++kt) {
      int ktok = kt * 16 + lcol;
      if (ktok >= 197) {
        #pragma unroll
        for (int r = 0; r < 4; ++r) s[kt][r] = -1e30f;
      } else {
        #pragma unroll
        for (int r = 0; r < 4; ++r) {
          int qq = strip * 16 + lrow4 + r;
          unsigned int bu = bt[qq * 224 + ktok];
          s[kt][r] += __builtin_bit_cast(float, bu << 16);
        }
      }
    }
    #pragma unroll
    for (int r = 0; r < 4; ++r) {
      float m = s[0][r];
      #pragma unroll
      for (int kt = 1; kt < 13; ++kt) m = fmaxf(m, s[kt][r]);
      #pragma unroll
      for (int d = 1; d < 16; d <<= 1) m = fmaxf(m, __shfl_xor(m, d));
      float sum = 0.0f;
      #pragma unroll
      for (int kt = 0; kt < 13; ++kt) { float p = __expf(s[kt][r] - m); s[kt][r] = p; sum += p; }
      #pragma unroll
      for (int d = 1; d < 16; d <<= 1) sum += __shfl_xor(sum, d);
      float rinv = 1.0f / sum;
      #pragma unroll
      for (int kt = 0; kt < 13; ++kt) s[kt][r] *= rinv;
    }
    #pragma unroll
    for (int kt = 0; kt < 13; ++kt)
      #pragma unroll
      for (int r = 0; r < 4; ++r)
        Ps[wv][lrow4 + r][kt * 16 + lcol] = f2bf(s[kt][r]);
    bf16x8 pa[7];
    #pragma unroll
    for (int kc = 0; kc < 7; ++kc)
      pa[kc] = *(const bf16x8*)(&Ps[wv][lcol][kc * 32 + lk8]);
    #pragma unroll
    for (int dt = 0; dt < 4; ++dt) {
      f32x4 oacc = {};
      #pragma unroll
      for (int kc = 0; kc < 7; ++kc) {
        bf16x8 bv = *(const bf16x8*)(&Vt[dt * 16 + lcol][kc * 32 + lk8]);
        oacc = __builtin_amdgcn_mfma_f32_16x16x32_bf16(pa[kc], bv, oacc, 0, 0, 0);
      }
      #pragma unroll
      for (int r = 0; r < 4; ++r) {
        int qq = strip * 16 + lrow4 + r;
        if (qq < 197)
          og[((long)b * 197 + qq) * 1024 + head * 64 + dt * 16 + lcol] = f2bf(oacc[r]);
      }
    }
  }
}

// ---------------- launch ----------------
extern "C" void kernel_launch(void* const* d_in, const int* in_sizes, int n_in,
                              void* d_out, int out_size, void* d_ws, size_t ws_size,
                              hipStream_t stream) {
  const float* x        = (const float*)d_in[0];
  const float* qkv_w    = (const float*)d_in[1];
  const float* q_bias   = (const float*)d_in[2];
  const float* v_bias   = (const float*)d_in[3];
  const float* rel_tab  = (const float*)d_in[4];
  const float* proj_w   = (const float*)d_in[5];
  const float* proj_b   = (const float*)d_in[6];
  const float* ln1_g    = (const float*)d_in[7];
  const float* ln1_b    = (const float*)d_in[8];
  const float* ln2_g    = (const float*)d_in[9];
  const float* ln2_b    = (const float*)d_in[10];
  const float* fc1_w    = (const float*)d_in[11];
  const float* fc1_b    = (const float*)d_in[12];
  const float* fc2_w    = (const float*)d_in[13];
  const float* fc2_b    = (const float*)d_in[14];
  float* out = (float*)d_out;
  char* ws = (char*)d_ws;

  const int M = 64 * 197;            // 12608
  const size_t MP = 12800;           // padded to 100*128
  const int RB = 100;                // M block rows (BM=128)

  size_t off = 0;
  auto take = [&](size_t bytes) { size_t o = off; off += (bytes + 255) & ~(size_t)255; return o; };
  size_t o_wqkv = take((size_t)3072 * 1024 * 2);
  size_t o_wproj = take((size_t)1024 * 1024 * 2);
  size_t o_wfc1 = take((size_t)4096 * 1024 * 2);
  size_t o_wfc2 = take((size_t)1024 * 4096 * 2);
  size_t o_big  = take(MP * 4096 * 2);          // h+q+k+v overlap g (fc1 out)
  size_t o_o    = take(MP * 1024 * 2);          // attn out, reused as h2
  size_t o_bias = take((size_t)16 * 208 * 224 * 2);

  unsigned short* wqkv = (unsigned short*)(ws + o_wqkv);
  unsigned short* wproj = (unsigned short*)(ws + o_wproj);
  unsigned short* wfc1 = (unsigned short*)(ws + o_wfc1);
  unsigned short* wfc2 = (unsigned short*)(ws + o_wfc2);
  unsigned short* h   = (unsigned short*)(ws + o_big);
  unsigned short* qb  = (unsigned short*)(ws + o_big + MP * 1024 * 2);
  unsigned short* kb  = qb + (size_t)64 * 16 * 197 * 64;
  unsigned short* vb  = kb + (size_t)64 * 16 * 197 * 64;
  unsigned short* g   = (unsigned short*)(ws + o_big);       // fc1 out (h,q,k,v dead)
  unsigned short* ob  = (unsigned short*)(ws + o_o);
  unsigned short* h2  = ob;                                   // reuse after proj
  unsigned short* btab = (unsigned short*)(ws + o_bias);
  float* x1 = out;                                            // residual-1 lives in d_out

  cvt_all<<<2048, 256, 0, stream>>>(qkv_w, wqkv, 3145728 / 4,
                                    proj_w, wproj, 1048576 / 4,
                                    fc1_w, wfc1, 4194304 / 4,
                                    fc2_w, wfc2, 4194304 / 4);

  build_bias<<<dim3(208, 16), 256, 0, stream>>>(rel_tab, btab);

  ln_kernel<<<M, 256, 0, stream>>>(x, ln1_g, ln1_b, h, M);

  gemm_f<0><<<RB * 12, 512, 49152, stream>>>(h, wqkv, M, 3072, 1024, 12,
      q_bias, v_bias, nullptr, qb, kb, vb, nullptr);

  attn_kernel<<<1024, 256, 0, stream>>>(qb, kb, vb, btab, ob);

  gemm_f<1><<<RB * 4, 512, 49152, stream>>>(ob, wproj, M, 1024, 1024, 4,
      proj_b, nullptr, x, nullptr, nullptr, nullptr, x1);

  ln_kernel<<<M, 256, 0, stream>>>(x1, ln2_g, ln2_b, h2, M);

  gemm_f<2><<<RB * 16, 512, 49152, stream>>>(h2, wfc1, M, 4096, 1024, 16,
      fc1_b, nullptr, nullptr, g, nullptr, nullptr, nullptr);

  gemm_f<3><<<RB * 4, 512, 49152, stream>>>(g, wfc2, M, 1024, 4096, 4,
      fc2_b, nullptr, x1, nullptr, nullptr, nullptr, out);
}